// Round 1
// baseline (671.888 us; speedup 1.0000x reference)
//
#include <hip/hip_runtime.h>

#define N_ROWS   131072
#define D_IN     512
#define D_H      128
#define K_CODES  256
#define NT       256          // 4 waves
#define RPB      128          // rows per block: 32 per wave (2 x 16-row MFMA tiles)
#define NBLK     (N_ROWS / RPB)
#define SA       136          // s_A row stride in bf16 elems (272 B, breaks power-of-2)

typedef __attribute__((ext_vector_type(8))) short bf16x8;
typedef __attribute__((ext_vector_type(4))) float f32x4;

__device__ inline unsigned short f2bf(float f) {
    unsigned u = __float_as_uint(f);
    return (unsigned short)((u + 0x7FFFu + ((u >> 16) & 1u)) >> 16);
}
__device__ inline ushort4 f2bf4(float4 v) {
    return make_ushort4(f2bf(v.x), f2bf(v.y), f2bf(v.z), f2bf(v.w));
}

// ---------------- prep: reorder weights/codebooks into MFMA B-fragment order ----------------
// B-fragment order: frag(ct,ks) is 64 lanes x 8 bf16, lane = qd*16+nn holds
// B[n = ct*16+nn][k = ks*32 + qd*8 + j], j=0..7.  One 32KB "round" = 8 ct x 4 ks.
// wsb layout (ushorts): [0..65535] Wenc rounds kc=0..3 | [65536..163839] cb (t,half) rounds | [163840..229375] Wdec rounds c=0..3
__global__ void rqvae_prep(const float* __restrict__ Wenc,
                           const float* __restrict__ Wdec,
                           const float* __restrict__ cb0,
                           const float* __restrict__ cb1,
                           const float* __restrict__ cb2,
                           unsigned short* __restrict__ wsb,
                           float* __restrict__ norms)
{
    const int tid = threadIdx.x;
    const int b = blockIdx.x;
    const float* cbs[3] = {cb0, cb1, cb2};
    if (b < 112) {
        const int g = b * 256 + tid;            // ushort8 group id, 0..28671
        const int lane = g & 63, ks = (g >> 6) & 3, ct = (g >> 8) & 7;
        const int nn = lane & 15, qd = lane >> 4;
        const float* src;
        if (g < 8192) {                         // Wenc: kc = g>>11
            const int kc = g >> 11;
            src = Wenc + (ct * 16 + nn) * D_IN + kc * 128 + ks * 32 + qd * 8;
        } else if (g < 20480) {                 // cb: t = (g-8192)>>12, half = bit 11
            const int r = g - 8192;
            const int t = r >> 12, half = (r >> 11) & 1;
            src = cbs[t] + (long)(half * 128 + ct * 16 + nn) * D_H + ks * 32 + qd * 8;
        } else {                                // Wdec: c = (g-20480)>>11
            const int r = g - 20480;
            const int c = r >> 11;
            src = Wdec + (long)(c * 128 + ct * 16 + nn) * D_H + ks * 32 + qd * 8;
        }
        float4 v0 = *(const float4*)(src);
        float4 v1 = *(const float4*)(src + 4);
        *(ushort4*)(wsb + (long)g * 8)     = f2bf4(v0);
        *(ushort4*)(wsb + (long)g * 8 + 4) = f2bf4(v1);
    } else {
        const int t = b - 112;                  // norm blocks: one code per thread
        const float4* r = (const float4*)(cbs[t] + (long)tid * D_H);
        float s = 0.f;
        #pragma unroll
        for (int d = 0; d < 32; ++d) { float4 v = r[d]; s += v.x*v.x + v.y*v.y + v.z*v.z + v.w*v.w; }
        norms[t * K_CODES + tid] = -0.5f * s;
    }
}

// ---------------- main ----------------
// Barrier-free design: B fragments are read straight from global wsb (L2-resident,
// frag-linear so each wave's 16B/lane load is a single coalesced global_load_dwordx4).
// s_A holds only wave-private rows (each wave stages its own 32 rows), so the ONLY
// __syncthreads in the kernel is the s_cn fill. 8 waves/CU run fully independent
// pipelines instead of lockstep stage->drain->compute.
__global__ __launch_bounds__(NT, 2) void rqvae_main(
    const float* __restrict__ emb,
    const float* __restrict__ cb0,
    const float* __restrict__ cb1,
    const float* __restrict__ cb2,
    const unsigned short* __restrict__ wsb,
    const float* __restrict__ norms,
    float* __restrict__ acc_rq,
    float* __restrict__ acc_recon,
    int* __restrict__ used)
{
    __shared__ unsigned short s_A[RPB * SA];   // 34816 B: A operand, wave-private rows, padded
    __shared__ float s_cn[3 * K_CODES];        // 3072 B
    // total LDS 37888 B

    const int tid  = threadIdx.x;
    const int wv   = tid >> 6;
    const int lane = tid & 63;
    const int nn   = lane & 15;
    const int qd   = lane >> 4;
    const long blkRow = (long)blockIdx.x * RPB;
    const float* cbs[3] = {cb0, cb1, cb2};
    const unsigned short* __restrict__ wlane = wsb + lane * 8;   // per-lane B base

    for (int i = tid; i < 3 * K_CODES; i += NT) s_cn[i] = norms[i];
    __syncthreads();   // the only barrier: make s_cn visible to all waves

    f32x4 rem[2][8], res[2][8];
    #pragma unroll
    for (int rt = 0; rt < 2; ++rt)
        #pragma unroll
        for (int ct = 0; ct < 8; ++ct) { rem[rt][ct] = {0.f,0.f,0.f,0.f}; res[rt][ct] = {0.f,0.f,0.f,0.f}; }

    // ---- Phase 1: latent = emb @ Wenc^T (4 rounds of K=128), A staged wave-private ----
    for (int kc = 0; kc < 4; ++kc) {
        #pragma unroll
        for (int it = 0; it < 16; ++it) {                   // this wave's 32 rows x 32 float4
            const int idx = lane + it * 64, rl = idx >> 5, c4 = idx & 31;
            float4 v = *(const float4*)(emb + (blkRow + wv * 32 + rl) * D_IN + kc * 128 + c4 * 4);
            *(ushort4*)&s_A[(wv * 32 + rl) * SA + c4 * 4] = f2bf4(v);
        }
        bf16x8 af[2][4];
        #pragma unroll
        for (int rt = 0; rt < 2; ++rt)
            #pragma unroll
            for (int ks = 0; ks < 4; ++ks)
                af[rt][ks] = *(const bf16x8*)&s_A[(wv * 32 + rt * 16 + nn) * SA + ks * 32 + qd * 8];
        const unsigned short* __restrict__ B = wlane + kc * 16384;
        #pragma unroll
        for (int ct = 0; ct < 8; ++ct)
            #pragma unroll
            for (int ks = 0; ks < 4; ++ks) {
                bf16x8 bf = *(const bf16x8*)(B + (ct * 4 + ks) * 512);
                rem[0][ct] = __builtin_amdgcn_mfma_f32_16x16x32_bf16(af[0][ks], bf, rem[0][ct], 0, 0, 0);
                rem[1][ct] = __builtin_amdgcn_mfma_f32_16x16x32_bf16(af[1][ks], bf, rem[1][ct], 0, 0, 0);
            }
    }

    // latent -> s_A bf16 (wave-private rows)
    #pragma unroll
    for (int rt = 0; rt < 2; ++rt)
        #pragma unroll
        for (int ct = 0; ct < 8; ++ct)
            #pragma unroll
            for (int e = 0; e < 4; ++e)
                s_A[(wv * 32 + rt * 16 + qd * 4 + e) * SA + ct * 16 + nn] = f2bf(rem[rt][ct][e]);

    // ---- Phase 2: three RQ stages ----
    float local_rq = 0.f;
    for (int t = 0; t < 3; ++t) {
        const float* __restrict__ cb = cbs[t];
        float bv[2][4]; int bi[2][4];
        #pragma unroll
        for (int rt = 0; rt < 2; ++rt)
            #pragma unroll
            for (int e = 0; e < 4; ++e) { bv[rt][e] = -3.402823466e38f; bi[rt][e] = 0; }

        bf16x8 af[2][4];
        #pragma unroll
        for (int rt = 0; rt < 2; ++rt)
            #pragma unroll
            for (int ks = 0; ks < 4; ++ks)
                af[rt][ks] = *(const bf16x8*)&s_A[(wv * 32 + rt * 16 + nn) * SA + ks * 32 + qd * 8];

        for (int half = 0; half < 2; ++half) {
            const unsigned short* __restrict__ B = wlane + 65536 + (t * 2 + half) * 16384;
            #pragma unroll
            for (int ct = 0; ct < 8; ++ct) {
                f32x4 s0 = {0.f,0.f,0.f,0.f}, s1 = {0.f,0.f,0.f,0.f};
                #pragma unroll
                for (int ks = 0; ks < 4; ++ks) {
                    bf16x8 bf = *(const bf16x8*)(B + (ct * 4 + ks) * 512);
                    s0 = __builtin_amdgcn_mfma_f32_16x16x32_bf16(af[0][ks], bf, s0, 0, 0, 0);
                    s1 = __builtin_amdgcn_mfma_f32_16x16x32_bf16(af[1][ks], bf, s1, 0, 0, 0);
                }
                const int code = half * 128 + ct * 16 + nn;
                const float cn = s_cn[t * K_CODES + code];
                #pragma unroll
                for (int e = 0; e < 4; ++e) {
                    const float v0 = s0[e] + cn;
                    if (v0 > bv[0][e] || (v0 == bv[0][e] && code < bi[0][e])) { bv[0][e] = v0; bi[0][e] = code; }
                    const float v1 = s1[e] + cn;
                    if (v1 > bv[1][e] || (v1 == bv[1][e] && code < bi[1][e])) { bv[1][e] = v1; bi[1][e] = code; }
                }
            }
        }
        // argmax over the 16 nn-lanes of each quad (tie -> lowest index)
        #pragma unroll
        for (int rt = 0; rt < 2; ++rt)
            #pragma unroll
            for (int e = 0; e < 4; ++e) {
                float v = bv[rt][e]; int i0 = bi[rt][e];
                #pragma unroll
                for (int m = 8; m >= 1; m >>= 1) {
                    const float ov = __shfl_xor(v, m);
                    const int   oi = __shfl_xor(i0, m);
                    if (ov > v || (ov == v && oi < i0)) { v = ov; i0 = oi; }
                }
                bi[rt][e] = i0;
                if (nn == 0) used[t * K_CODES + i0] = 1;
            }
        // update rem/res with fp32 codebook rows
        #pragma unroll
        for (int rt = 0; rt < 2; ++rt)
            #pragma unroll
            for (int ct = 0; ct < 8; ++ct)
                #pragma unroll
                for (int e = 0; e < 4; ++e) {
                    const float c = cb[(long)bi[rt][e] * D_H + ct * 16 + nn];
                    const float r = rem[rt][ct][e] - c;
                    rem[rt][ct][e] = r;
                    res[rt][ct][e] += c;
                    local_rq += r * r;
                    if (t < 2)
                        s_A[(wv * 32 + rt * 16 + qd * 4 + e) * SA + ct * 16 + nn] = f2bf(r);
                }
    }

    // restored -> s_A bf16 (wave-private)
    #pragma unroll
    for (int rt = 0; rt < 2; ++rt)
        #pragma unroll
        for (int ct = 0; ct < 8; ++ct)
            #pragma unroll
            for (int e = 0; e < 4; ++e)
                s_A[(wv * 32 + rt * 16 + qd * 4 + e) * SA + ct * 16 + nn] = f2bf(res[rt][ct][e]);

    // ---- Phase 3: recon = restored @ Wdec^T, diff vs fp32 emb ----
    float local_rec = 0.f;
    {
        bf16x8 af[2][4];
        #pragma unroll
        for (int rt = 0; rt < 2; ++rt)
            #pragma unroll
            for (int ks = 0; ks < 4; ++ks)
                af[rt][ks] = *(const bf16x8*)&s_A[(wv * 32 + rt * 16 + nn) * SA + ks * 32 + qd * 8];
        for (int c = 0; c < 4; ++c) {
            const unsigned short* __restrict__ B = wlane + 163840 + c * 16384;
            #pragma unroll
            for (int ct = 0; ct < 8; ++ct) {
                f32x4 r0 = {0.f,0.f,0.f,0.f}, r1 = {0.f,0.f,0.f,0.f};
                #pragma unroll
                for (int ks = 0; ks < 4; ++ks) {
                    bf16x8 bf = *(const bf16x8*)(B + (ct * 4 + ks) * 512);
                    r0 = __builtin_amdgcn_mfma_f32_16x16x32_bf16(af[0][ks], bf, r0, 0, 0, 0);
                    r1 = __builtin_amdgcn_mfma_f32_16x16x32_bf16(af[1][ks], bf, r1, 0, 0, 0);
                }
                const int col = c * 128 + ct * 16 + nn;
                #pragma unroll
                for (int e = 0; e < 4; ++e) {
                    const float e0 = emb[(blkRow + wv * 32 +      qd * 4 + e) * D_IN + col];
                    const float e1 = emb[(blkRow + wv * 32 + 16 + qd * 4 + e) * D_IN + col];
                    const float d0 = r0[e] - e0;
                    const float d1 = r1[e] - e1;
                    local_rec += d0 * d0 + d1 * d1;
                }
            }
        }
    }

    // ---- wave shuffle reduce, one atomic pair per wave ----
    float r1 = local_rq, r2 = local_rec;
    #pragma unroll
    for (int m = 32; m >= 1; m >>= 1) { r1 += __shfl_xor(r1, m); r2 += __shfl_xor(r2, m); }
    if (lane == 0) { atomicAdd(acc_rq, r1); atomicAdd(acc_recon, r2); }
}

__global__ void rqvae_finalize(const float* __restrict__ acc,
                               const int* __restrict__ used,
                               float* __restrict__ out)
{
    __shared__ int s_sum[4];
    const int tid = threadIdx.x;
    for (int t = 0; t < 3; ++t) {
        int v = (used[t * K_CODES + tid] != 0) ? 1 : 0;
        #pragma unroll
        for (int off = 32; off >= 1; off >>= 1) v += __shfl_down(v, off);
        if ((tid & 63) == 0) s_sum[tid >> 6] = v;
        __syncthreads();
        if (tid == 0) out[3 + t] = (float)(s_sum[0] + s_sum[1] + s_sum[2] + s_sum[3]);
        __syncthreads();
    }
    if (tid == 0) {
        const float rq    = 1.25f * acc[0] / ((float)N_ROWS * 128.0f);
        const float recon =         acc[1] / ((float)N_ROWS * 512.0f);
        out[0] = recon + rq;
        out[1] = recon;
        out[2] = rq;
    }
}

extern "C" void kernel_launch(void* const* d_in, const int* in_sizes, int n_in,
                              void* d_out, int out_size, void* d_ws, size_t ws_size,
                              hipStream_t stream) {
    const float* emb  = (const float*)d_in[0];
    const float* Wenc = (const float*)d_in[1];
    const float* Wdec = (const float*)d_in[2];
    const float* cb0  = (const float*)d_in[3];
    const float* cb1  = (const float*)d_in[4];
    const float* cb2  = (const float*)d_in[5];

    // workspace layout (bytes): [0] 2 f32 acc | [64] 768 int used | [3200] 768 f32 norms | [8192] 448KB bf16 frags
    float* ws_f  = (float*)d_ws;
    int*   used  = (int*)((char*)d_ws + 64);
    float* norms = (float*)((char*)d_ws + 3200);
    unsigned short* wsb = (unsigned short*)((char*)d_ws + 8192);

    hipMemsetAsync(d_ws, 0, 3200, stream);
    rqvae_prep<<<115, NT, 0, stream>>>(Wenc, Wdec, cb0, cb1, cb2, wsb, norms);
    rqvae_main<<<NBLK, NT, 0, stream>>>(emb, cb0, cb1, cb2, wsb, norms,
                                        ws_f + 0, ws_f + 1, used);
    rqvae_finalize<<<1, K_CODES, 0, stream>>>(ws_f, used, (float*)d_out);
}

// Round 2
// 623.291 us; speedup vs baseline: 1.0780x; 1.0780x over previous
//
#include <hip/hip_runtime.h>

#define N_ROWS   131072
#define D_IN     512
#define D_H      128
#define K_CODES  256
#define NT       256          // 4 waves
#define RPB      64           // rows per block: 16 per wave (1 x 16-row MFMA tile)
#define NBLK     (N_ROWS / RPB)
#define SA       136          // s_A row stride in bf16 elems (272 B, breaks power-of-2)

typedef __attribute__((ext_vector_type(8))) short bf16x8;
typedef __attribute__((ext_vector_type(4))) float f32x4;

__device__ inline unsigned short f2bf(float f) {
    unsigned u = __float_as_uint(f);
    return (unsigned short)((u + 0x7FFFu + ((u >> 16) & 1u)) >> 16);
}
__device__ inline ushort4 f2bf4(float4 v) {
    return make_ushort4(f2bf(v.x), f2bf(v.y), f2bf(v.z), f2bf(v.w));
}
__device__ inline bf16x8 f2bf8(float4 a, float4 b) {
    bf16x8 r;
    r[0] = (short)f2bf(a.x); r[1] = (short)f2bf(a.y); r[2] = (short)f2bf(a.z); r[3] = (short)f2bf(a.w);
    r[4] = (short)f2bf(b.x); r[5] = (short)f2bf(b.y); r[6] = (short)f2bf(b.z); r[7] = (short)f2bf(b.w);
    return r;
}

// async global->LDS DMA, 16B per lane; LDS dest is wave-uniform base + lane*16
typedef const __attribute__((address_space(1))) void* gv_t;
typedef __attribute__((address_space(3))) void* lv_t;
__device__ __forceinline__ void gll16(const unsigned short* g, unsigned short* l) {
    __builtin_amdgcn_global_load_lds((gv_t)g, (lv_t)l, 16, 0, 0);
}

// ---------------- prep: reorder weights/codebooks into MFMA B-fragment order ----------------
// B-fragment order: frag(ct,ks) is 64 lanes x 8 bf16, lane = qd*16+nn holds
// B[n = ct*16+nn][k = ks*32 + qd*8 + j], j=0..7.  One 32KB "round" = 8 ct x 4 ks.
// wsb layout (ushorts): [0..65535] Wenc rounds kc=0..3 | [65536..163839] cb (t,half) rounds | [163840..229375] Wdec rounds c=0..3
__global__ void rqvae_prep(const float* __restrict__ Wenc,
                           const float* __restrict__ Wdec,
                           const float* __restrict__ cb0,
                           const float* __restrict__ cb1,
                           const float* __restrict__ cb2,
                           unsigned short* __restrict__ wsb,
                           float* __restrict__ norms)
{
    const int tid = threadIdx.x;
    const int b = blockIdx.x;
    const float* cbs[3] = {cb0, cb1, cb2};
    if (b < 112) {
        const int g = b * 256 + tid;            // ushort8 group id, 0..28671
        const int lane = g & 63, ks = (g >> 6) & 3, ct = (g >> 8) & 7;
        const int nn = lane & 15, qd = lane >> 4;
        const float* src;
        if (g < 8192) {                         // Wenc: kc = g>>11
            const int kc = g >> 11;
            src = Wenc + (ct * 16 + nn) * D_IN + kc * 128 + ks * 32 + qd * 8;
        } else if (g < 20480) {                 // cb: t = (g-8192)>>12, half = bit 11
            const int r = g - 8192;
            const int t = r >> 12, half = (r >> 11) & 1;
            src = cbs[t] + (long)(half * 128 + ct * 16 + nn) * D_H + ks * 32 + qd * 8;
        } else {                                // Wdec: c = (g-20480)>>11
            const int r = g - 20480;
            const int c = r >> 11;
            src = Wdec + (long)(c * 128 + ct * 16 + nn) * D_H + ks * 32 + qd * 8;
        }
        float4 v0 = *(const float4*)(src);
        float4 v1 = *(const float4*)(src + 4);
        *(ushort4*)(wsb + (long)g * 8)     = f2bf4(v0);
        *(ushort4*)(wsb + (long)g * 8 + 4) = f2bf4(v1);
    } else {
        const int t = b - 112;                  // norm blocks: one code per thread
        const float4* r = (const float4*)(cbs[t] + (long)tid * D_H);
        float s = 0.f;
        #pragma unroll
        for (int d = 0; d < 32; ++d) { float4 v = r[d]; s += v.x*v.x + v.y*v.y + v.z*v.z + v.w*v.w; }
        norms[t * K_CODES + tid] = -0.5f * s;
    }
}

// ---------------- main ----------------
// RPB=64 (16 rows/wave): halves registers and s_A vs the 128-row version ->
// 3-4 blocks/CU (12-16 waves) instead of 2 (8 waves). B staged to LDS via
// global_load_lds DMA in 16KB rounds (single buffer, sync;stage;sync;compute);
// phase-1 A loaded straight to register fragments (no LDS round trip).
__global__ __launch_bounds__(NT, 3) void rqvae_main(
    const float* __restrict__ emb,
    const float* __restrict__ cb0,
    const float* __restrict__ cb1,
    const float* __restrict__ cb2,
    const unsigned short* __restrict__ wsb,
    const float* __restrict__ norms,
    float* __restrict__ acc_rq,
    float* __restrict__ acc_recon,
    int* __restrict__ used)
{
    __shared__ unsigned short s_A[RPB * SA];   // 17408 B: A operand (rem/restored), wave-private rows
    __shared__ unsigned short s_B[8192];       // 16384 B: one 16KB B round, fragment-linear
    __shared__ float s_cn[3 * K_CODES];        // 3072 B -> total 36864 B (4 blocks/CU by LDS)

    const int tid  = threadIdx.x;
    const int wv   = tid >> 6;
    const int lane = tid & 63;
    const int nn   = lane & 15;
    const int qd   = lane >> 4;
    const int wrow = wv * 16;                  // this wave's 16 rows in the block
    const long blkRow = (long)blockIdx.x * RPB;
    const float* cbs[3] = {cb0, cb1, cb2};

    for (int i = tid; i < 3 * K_CODES; i += NT) s_cn[i] = norms[i];

    f32x4 rem[8];
    #pragma unroll
    for (int ct = 0; ct < 8; ++ct) rem[ct] = {0.f,0.f,0.f,0.f};

    // ---- Phase 1: latent = emb @ Wenc^T; A direct global->reg, B 16KB LDS rounds ----
    for (int kc = 0; kc < 4; ++kc) {
        bf16x8 af[4];
        const float* arow = emb + (blkRow + wrow + nn) * D_IN + kc * 128 + qd * 8;
        #pragma unroll
        for (int ks = 0; ks < 4; ++ks)
            af[ks] = f2bf8(*(const float4*)(arow + ks * 32), *(const float4*)(arow + ks * 32 + 4));
        #pragma unroll
        for (int ch = 0; ch < 2; ++ch) {
            __syncthreads();                   // prev round's readers done with s_B
            {
                const unsigned short* src = wsb + kc * 16384 + ch * 8192;
                #pragma unroll
                for (int i = 0; i < 4; ++i)
                    gll16(src + i * 2048 + wv * 512 + lane * 8, s_B + i * 2048 + wv * 512);
            }
            __syncthreads();                   // drains vmcnt -> B visible
            __builtin_amdgcn_s_setprio(1);
            #pragma unroll
            for (int ctc = 0; ctc < 4; ++ctc)
                #pragma unroll
                for (int ks = 0; ks < 4; ++ks) {
                    bf16x8 bf = *(const bf16x8*)&s_B[(ctc * 4 + ks) * 512 + lane * 8];
                    rem[ch * 4 + ctc] = __builtin_amdgcn_mfma_f32_16x16x32_bf16(af[ks], bf, rem[ch * 4 + ctc], 0, 0, 0);
                }
            __builtin_amdgcn_s_setprio(0);
        }
    }

    // latent -> s_A bf16 (wave-private rows); init res here to shorten live range
    f32x4 res[8];
    #pragma unroll
    for (int ct = 0; ct < 8; ++ct) {
        res[ct] = {0.f,0.f,0.f,0.f};
        #pragma unroll
        for (int e = 0; e < 4; ++e)
            s_A[(wrow + qd * 4 + e) * SA + ct * 16 + nn] = f2bf(rem[ct][e]);
    }

    // ---- Phase 2: three RQ stages, B = 4 x 16KB rounds per stage ----
    float local_rq = 0.f;
    for (int t = 0; t < 3; ++t) {
        const float* __restrict__ cb = cbs[t];
        float bv[4]; int bi[4];
        #pragma unroll
        for (int e = 0; e < 4; ++e) { bv[e] = -3.402823466e38f; bi[e] = 0; }

        bf16x8 af[4];
        #pragma unroll
        for (int ks = 0; ks < 4; ++ks)
            af[ks] = *(const bf16x8*)&s_A[(wrow + nn) * SA + ks * 32 + qd * 8];

        for (int r = 0; r < 4; ++r) {
            __syncthreads();
            {
                const unsigned short* src = wsb + 65536 + t * 32768 + r * 8192;
                #pragma unroll
                for (int i = 0; i < 4; ++i)
                    gll16(src + i * 2048 + wv * 512 + lane * 8, s_B + i * 2048 + wv * 512);
            }
            __syncthreads();
            #pragma unroll
            for (int ctc = 0; ctc < 4; ++ctc) {
                f32x4 s = {0.f,0.f,0.f,0.f};
                __builtin_amdgcn_s_setprio(1);
                #pragma unroll
                for (int ks = 0; ks < 4; ++ks) {
                    bf16x8 bf = *(const bf16x8*)&s_B[(ctc * 4 + ks) * 512 + lane * 8];
                    s = __builtin_amdgcn_mfma_f32_16x16x32_bf16(af[ks], bf, s, 0, 0, 0);
                }
                __builtin_amdgcn_s_setprio(0);
                const int code = r * 64 + ctc * 16 + nn;
                const float cn = s_cn[t * K_CODES + code];
                #pragma unroll
                for (int e = 0; e < 4; ++e) {
                    const float v = s[e] + cn;
                    if (v > bv[e] || (v == bv[e] && code < bi[e])) { bv[e] = v; bi[e] = code; }
                }
            }
        }
        // argmax over the 16 nn-lanes of each quad (tie -> lowest index)
        #pragma unroll
        for (int e = 0; e < 4; ++e) {
            float v = bv[e]; int i0 = bi[e];
            #pragma unroll
            for (int m = 8; m >= 1; m >>= 1) {
                const float ov = __shfl_xor(v, m);
                const int   oi = __shfl_xor(i0, m);
                if (ov > v || (ov == v && oi < i0)) { v = ov; i0 = oi; }
            }
            bi[e] = i0;
            if (nn == 0) used[t * K_CODES + i0] = 1;
        }
        // update rem/res with fp32 codebook rows
        #pragma unroll
        for (int ct = 0; ct < 8; ++ct)
            #pragma unroll
            for (int e = 0; e < 4; ++e) {
                const float c = cb[(long)bi[e] * D_H + ct * 16 + nn];
                const float rr = rem[ct][e] - c;
                rem[ct][e] = rr;
                res[ct][e] += c;
                local_rq += rr * rr;
                if (t < 2)
                    s_A[(wrow + qd * 4 + e) * SA + ct * 16 + nn] = f2bf(rr);
            }
    }

    // restored -> s_A bf16 (wave-private)
    #pragma unroll
    for (int ct = 0; ct < 8; ++ct)
        #pragma unroll
        for (int e = 0; e < 4; ++e)
            s_A[(wrow + qd * 4 + e) * SA + ct * 16 + nn] = f2bf(res[ct][e]);

    // ---- Phase 3: recon = restored @ Wdec^T, diff vs fp32 emb ----
    float local_rec = 0.f;
    {
        bf16x8 af[4];
        #pragma unroll
        for (int ks = 0; ks < 4; ++ks)
            af[ks] = *(const bf16x8*)&s_A[(wrow + nn) * SA + ks * 32 + qd * 8];
        for (int c = 0; c < 4; ++c)
            for (int ch = 0; ch < 2; ++ch) {
                __syncthreads();
                {
                    const unsigned short* src = wsb + 163840 + c * 16384 + ch * 8192;
                    #pragma unroll
                    for (int i = 0; i < 4; ++i)
                        gll16(src + i * 2048 + wv * 512 + lane * 8, s_B + i * 2048 + wv * 512);
                }
                __syncthreads();
                #pragma unroll
                for (int ctc = 0; ctc < 4; ++ctc) {
                    f32x4 rr = {0.f,0.f,0.f,0.f};
                    __builtin_amdgcn_s_setprio(1);
                    #pragma unroll
                    for (int ks = 0; ks < 4; ++ks) {
                        bf16x8 bf = *(const bf16x8*)&s_B[(ctc * 4 + ks) * 512 + lane * 8];
                        rr = __builtin_amdgcn_mfma_f32_16x16x32_bf16(af[ks], bf, rr, 0, 0, 0);
                    }
                    __builtin_amdgcn_s_setprio(0);
                    const int col = c * 128 + (ch * 4 + ctc) * 16 + nn;
                    #pragma unroll
                    for (int e = 0; e < 4; ++e) {
                        const float e0 = emb[(blkRow + wrow + qd * 4 + e) * D_IN + col];
                        const float d = rr[e] - e0;
                        local_rec += d * d;
                    }
                }
            }
    }

    // ---- wave shuffle reduce, one atomic pair per wave ----
    float r1 = local_rq, r2 = local_rec;
    #pragma unroll
    for (int m = 32; m >= 1; m >>= 1) { r1 += __shfl_xor(r1, m); r2 += __shfl_xor(r2, m); }
    if (lane == 0) { atomicAdd(acc_rq, r1); atomicAdd(acc_recon, r2); }
}

__global__ void rqvae_finalize(const float* __restrict__ acc,
                               const int* __restrict__ used,
                               float* __restrict__ out)
{
    __shared__ int s_sum[4];
    const int tid = threadIdx.x;
    for (int t = 0; t < 3; ++t) {
        int v = (used[t * K_CODES + tid] != 0) ? 1 : 0;
        #pragma unroll
        for (int off = 32; off >= 1; off >>= 1) v += __shfl_down(v, off);
        if ((tid & 63) == 0) s_sum[tid >> 6] = v;
        __syncthreads();
        if (tid == 0) out[3 + t] = (float)(s_sum[0] + s_sum[1] + s_sum[2] + s_sum[3]);
        __syncthreads();
    }
    if (tid == 0) {
        const float rq    = 1.25f * acc[0] / ((float)N_ROWS * 128.0f);
        const float recon =         acc[1] / ((float)N_ROWS * 512.0f);
        out[0] = recon + rq;
        out[1] = recon;
        out[2] = rq;
    }
}

extern "C" void kernel_launch(void* const* d_in, const int* in_sizes, int n_in,
                              void* d_out, int out_size, void* d_ws, size_t ws_size,
                              hipStream_t stream) {
    const float* emb  = (const float*)d_in[0];
    const float* Wenc = (const float*)d_in[1];
    const float* Wdec = (const float*)d_in[2];
    const float* cb0  = (const float*)d_in[3];
    const float* cb1  = (const float*)d_in[4];
    const float* cb2  = (const float*)d_in[5];

    // workspace layout (bytes): [0] 2 f32 acc | [64] 768 int used | [3200] 768 f32 norms | [8192] 448KB bf16 frags
    float* ws_f  = (float*)d_ws;
    int*   used  = (int*)((char*)d_ws + 64);
    float* norms = (float*)((char*)d_ws + 3200);
    unsigned short* wsb = (unsigned short*)((char*)d_ws + 8192);

    hipMemsetAsync(d_ws, 0, 3200, stream);
    rqvae_prep<<<115, NT, 0, stream>>>(Wenc, Wdec, cb0, cb1, cb2, wsb, norms);
    rqvae_main<<<NBLK, NT, 0, stream>>>(emb, cb0, cb1, cb2, wsb, norms,
                                        ws_f + 0, ws_f + 1, used);
    rqvae_finalize<<<1, K_CODES, 0, stream>>>(ws_f, used, (float*)d_out);
}

// Round 3
// 601.617 us; speedup vs baseline: 1.1168x; 1.0360x over previous
//
#include <hip/hip_runtime.h>

#define N_ROWS   131072
#define D_IN     512
#define D_H      128
#define K_CODES  256
#define NT       256          // 4 waves
#define RPB      128          // rows per block: 32 per wave (2 x 16-row MFMA tiles)
#define NBLK     (N_ROWS / RPB)
#define SA       136          // s_A row stride in bf16 elems (272 B, breaks power-of-2)
#define NROUND   28           // 28 x 16KB B rounds = whole wsb, consumed linearly

typedef __attribute__((ext_vector_type(8))) short bf16x8;
typedef __attribute__((ext_vector_type(4))) float f32x4;

__device__ inline unsigned short f2bf(float f) {
    unsigned u = __float_as_uint(f);
    return (unsigned short)((u + 0x7FFFu + ((u >> 16) & 1u)) >> 16);
}
__device__ inline ushort4 f2bf4(float4 v) {
    return make_ushort4(f2bf(v.x), f2bf(v.y), f2bf(v.z), f2bf(v.w));
}
__device__ inline bf16x8 f2bf8(float4 a, float4 b) {
    bf16x8 r;
    r[0] = (short)f2bf(a.x); r[1] = (short)f2bf(a.y); r[2] = (short)f2bf(a.z); r[3] = (short)f2bf(a.w);
    r[4] = (short)f2bf(b.x); r[5] = (short)f2bf(b.y); r[6] = (short)f2bf(b.z); r[7] = (short)f2bf(b.w);
    return r;
}

// async global->LDS DMA, 16B per lane; LDS dest is wave-uniform base + lane*16
typedef const __attribute__((address_space(1))) void* gv_t;
typedef __attribute__((address_space(3))) void* lv_t;
__device__ __forceinline__ void gll16(const unsigned short* g, unsigned short* l) {
    __builtin_amdgcn_global_load_lds((gv_t)g, (lv_t)l, 16, 0, 0);
}

// ---------------- prep: reorder weights/codebooks into MFMA B-fragment order ----------------
// B-fragment order: frag(ct,ks) is 64 lanes x 8 bf16, lane = qd*16+nn holds
// B[n = ct*16+nn][k = ks*32 + qd*8 + j], j=0..7.  One 32KB "round" = 8 ct x 4 ks.
// wsb layout (ushorts): [0..65535] Wenc rounds kc=0..3 | [65536..163839] cb (t,half) rounds | [163840..229375] Wdec rounds c=0..3
__global__ void rqvae_prep(const float* __restrict__ Wenc,
                           const float* __restrict__ Wdec,
                           const float* __restrict__ cb0,
                           const float* __restrict__ cb1,
                           const float* __restrict__ cb2,
                           unsigned short* __restrict__ wsb,
                           float* __restrict__ norms)
{
    const int tid = threadIdx.x;
    const int b = blockIdx.x;
    const float* cbs[3] = {cb0, cb1, cb2};
    if (b < 112) {
        const int g = b * 256 + tid;            // ushort8 group id, 0..28671
        const int lane = g & 63, ks = (g >> 6) & 3, ct = (g >> 8) & 7;
        const int nn = lane & 15, qd = lane >> 4;
        const float* src;
        if (g < 8192) {                         // Wenc: kc = g>>11
            const int kc = g >> 11;
            src = Wenc + (ct * 16 + nn) * D_IN + kc * 128 + ks * 32 + qd * 8;
        } else if (g < 20480) {                 // cb: t = (g-8192)>>12, half = bit 11
            const int r = g - 8192;
            const int t = r >> 12, half = (r >> 11) & 1;
            src = cbs[t] + (long)(half * 128 + ct * 16 + nn) * D_H + ks * 32 + qd * 8;
        } else {                                // Wdec: c = (g-20480)>>11
            const int r = g - 20480;
            const int c = r >> 11;
            src = Wdec + (long)(c * 128 + ct * 16 + nn) * D_H + ks * 32 + qd * 8;
        }
        float4 v0 = *(const float4*)(src);
        float4 v1 = *(const float4*)(src + 4);
        *(ushort4*)(wsb + (long)g * 8)     = f2bf4(v0);
        *(ushort4*)(wsb + (long)g * 8 + 4) = f2bf4(v1);
    } else {
        const int t = b - 112;                  // norm blocks: one code per thread
        const float4* r = (const float4*)(cbs[t] + (long)tid * D_H);
        float s = 0.f;
        #pragma unroll
        for (int d = 0; d < 32; ++d) { float4 v = r[d]; s += v.x*v.x + v.y*v.y + v.z*v.z + v.w*v.w; }
        norms[t * K_CODES + tid] = -0.5f * s;
    }
}

// ---------------- main ----------------
// Round-0 geometry (RPB=128, 4 waves, 2 blocks/CU) + ONE change: B staging is a
// continuous 28-round double-buffered global_load_lds pipeline. Per round:
// STAGE(next -> other buf) ; MFMA(cur buf) ; __syncthreads (drains next's loads
// AFTER compute, hiding the L2 stage latency). Buffer r lives in buf[r&1];
// STAGE(r+1) targets the buffer last read at round r-1, already released at
// that round's barrier -> race-free with one barrier per round.
// Phase-1 A goes direct global->register (bit-identical bf16 path, no LDS trip).
__global__ __launch_bounds__(NT, 2) void rqvae_main(
    const float* __restrict__ emb,
    const float* __restrict__ cb0,
    const float* __restrict__ cb1,
    const float* __restrict__ cb2,
    const unsigned short* __restrict__ wsb,
    const float* __restrict__ norms,
    float* __restrict__ acc_rq,
    float* __restrict__ acc_recon,
    int* __restrict__ used)
{
    __shared__ unsigned short s_A[RPB * SA];   // 34816 B: latent/rem/restored, wave-private rows
    __shared__ unsigned short s_B[2][8192];    // 32768 B: double-buffered 16KB B rounds
    __shared__ float s_cn[3 * K_CODES];        // 3072 B  -> total 70656 B, 2 blocks/CU

    const int tid  = threadIdx.x;
    const int wv   = tid >> 6;
    const int lane = tid & 63;
    const int nn   = lane & 15;
    const int qd   = lane >> 4;
    const int wrow = wv * 32;                  // this wave's 32 rows in the block
    const long blkRow = (long)blockIdx.x * RPB;
    const float* cbs[3] = {cb0, cb1, cb2};

    for (int i = tid; i < 3 * K_CODES; i += NT) s_cn[i] = norms[i];

#define STAGE(r, buf) do {                                                      \
        const unsigned short* _s = wsb + (r) * 8192;                            \
        _Pragma("unroll")                                                       \
        for (int _i = 0; _i < 4; ++_i)                                          \
            gll16(_s + _i * 2048 + wv * 512 + lane * 8,                         \
                  &s_B[buf][_i * 2048 + wv * 512]);                             \
    } while (0)

    STAGE(0, 0);
    __syncthreads();                           // round-0 data + s_cn visible
    int cur = 0;

    f32x4 rem[2][8], res[2][8];
    #pragma unroll
    for (int rt = 0; rt < 2; ++rt)
        #pragma unroll
        for (int ct = 0; ct < 8; ++ct) { rem[rt][ct] = {0.f,0.f,0.f,0.f}; res[rt][ct] = {0.f,0.f,0.f,0.f}; }

    // ---- Phase 1: latent = emb @ Wenc^T; rounds 0..7, A direct global->reg ----
    for (int kc = 0; kc < 4; ++kc) {
        STAGE(kc * 2 + 1, cur ^ 1);            // prefetch before the A-load stall
        bf16x8 af[2][4];
        #pragma unroll
        for (int rt = 0; rt < 2; ++rt) {
            const float* arow = emb + (blkRow + wrow + rt * 16 + nn) * D_IN + kc * 128 + qd * 8;
            #pragma unroll
            for (int ks = 0; ks < 4; ++ks)
                af[rt][ks] = f2bf8(*(const float4*)(arow + ks * 32), *(const float4*)(arow + ks * 32 + 4));
        }
        // ch = 0 : round kc*2, ct = 0..3
        __builtin_amdgcn_s_setprio(1);
        #pragma unroll
        for (int ctc = 0; ctc < 4; ++ctc)
            #pragma unroll
            for (int ks = 0; ks < 4; ++ks) {
                bf16x8 bf = *(const bf16x8*)&s_B[cur][(ctc * 4 + ks) * 512 + lane * 8];
                rem[0][ctc] = __builtin_amdgcn_mfma_f32_16x16x32_bf16(af[0][ks], bf, rem[0][ctc], 0, 0, 0);
                rem[1][ctc] = __builtin_amdgcn_mfma_f32_16x16x32_bf16(af[1][ks], bf, rem[1][ctc], 0, 0, 0);
            }
        __builtin_amdgcn_s_setprio(0);
        __syncthreads(); cur ^= 1;
        STAGE(kc * 2 + 2, cur ^ 1);            // kc=3 stages round 8 = first phase-2 round
        // ch = 1 : round kc*2+1, ct = 4..7
        __builtin_amdgcn_s_setprio(1);
        #pragma unroll
        for (int ctc = 0; ctc < 4; ++ctc)
            #pragma unroll
            for (int ks = 0; ks < 4; ++ks) {
                bf16x8 bf = *(const bf16x8*)&s_B[cur][(ctc * 4 + ks) * 512 + lane * 8];
                rem[0][4 + ctc] = __builtin_amdgcn_mfma_f32_16x16x32_bf16(af[0][ks], bf, rem[0][4 + ctc], 0, 0, 0);
                rem[1][4 + ctc] = __builtin_amdgcn_mfma_f32_16x16x32_bf16(af[1][ks], bf, rem[1][4 + ctc], 0, 0, 0);
            }
        __builtin_amdgcn_s_setprio(0);
        __syncthreads(); cur ^= 1;
    }

    // latent -> s_A bf16 (wave-private rows)
    #pragma unroll
    for (int rt = 0; rt < 2; ++rt)
        #pragma unroll
        for (int ct = 0; ct < 8; ++ct)
            #pragma unroll
            for (int e = 0; e < 4; ++e)
                s_A[(wrow + rt * 16 + qd * 4 + e) * SA + ct * 16 + nn] = f2bf(rem[rt][ct][e]);

    // ---- Phase 2: three RQ stages; rounds 8..19 (4 x 16KB per stage) ----
    float local_rq = 0.f;
    for (int t = 0; t < 3; ++t) {
        const float* __restrict__ cb = cbs[t];
        float bv[2][4]; int bi[2][4];
        #pragma unroll
        for (int rt = 0; rt < 2; ++rt)
            #pragma unroll
            for (int e = 0; e < 4; ++e) { bv[rt][e] = -3.402823466e38f; bi[rt][e] = 0; }

        bf16x8 af[2][4];
        #pragma unroll
        for (int rt = 0; rt < 2; ++rt)
            #pragma unroll
            for (int ks = 0; ks < 4; ++ks)
                af[rt][ks] = *(const bf16x8*)&s_A[(wrow + rt * 16 + nn) * SA + ks * 32 + qd * 8];

        #pragma unroll
        for (int rl = 0; rl < 4; ++rl) {
            const int r = 8 + t * 4 + rl;
            STAGE(r + 1, cur ^ 1);             // r+1 <= 20, always valid
            __builtin_amdgcn_s_setprio(1);
            #pragma unroll
            for (int ctc = 0; ctc < 4; ++ctc) {
                f32x4 s0 = {0.f,0.f,0.f,0.f}, s1 = {0.f,0.f,0.f,0.f};
                #pragma unroll
                for (int ks = 0; ks < 4; ++ks) {
                    bf16x8 bf = *(const bf16x8*)&s_B[cur][(ctc * 4 + ks) * 512 + lane * 8];
                    s0 = __builtin_amdgcn_mfma_f32_16x16x32_bf16(af[0][ks], bf, s0, 0, 0, 0);
                    s1 = __builtin_amdgcn_mfma_f32_16x16x32_bf16(af[1][ks], bf, s1, 0, 0, 0);
                }
                const int code = rl * 64 + ctc * 16 + nn;
                const float cn = s_cn[t * K_CODES + code];
                #pragma unroll
                for (int e = 0; e < 4; ++e) {
                    const float v0 = s0[e] + cn;
                    if (v0 > bv[0][e] || (v0 == bv[0][e] && code < bi[0][e])) { bv[0][e] = v0; bi[0][e] = code; }
                    const float v1 = s1[e] + cn;
                    if (v1 > bv[1][e] || (v1 == bv[1][e] && code < bi[1][e])) { bv[1][e] = v1; bi[1][e] = code; }
                }
            }
            __builtin_amdgcn_s_setprio(0);
            __syncthreads(); cur ^= 1;
        }
        // argmax over the 16 nn-lanes of each quad (tie -> lowest index)
        #pragma unroll
        for (int rt = 0; rt < 2; ++rt)
            #pragma unroll
            for (int e = 0; e < 4; ++e) {
                float v = bv[rt][e]; int i0 = bi[rt][e];
                #pragma unroll
                for (int m = 8; m >= 1; m >>= 1) {
                    const float ov = __shfl_xor(v, m);
                    const int   oi = __shfl_xor(i0, m);
                    if (ov > v || (ov == v && oi < i0)) { v = ov; i0 = oi; }
                }
                bi[rt][e] = i0;
                if (nn == 0) used[t * K_CODES + i0] = 1;
            }
        // update rem/res with fp32 codebook rows
        #pragma unroll
        for (int rt = 0; rt < 2; ++rt)
            #pragma unroll
            for (int ct = 0; ct < 8; ++ct)
                #pragma unroll
                for (int e = 0; e < 4; ++e) {
                    const float c = cb[(long)bi[rt][e] * D_H + ct * 16 + nn];
                    const float rr = rem[rt][ct][e] - c;
                    rem[rt][ct][e] = rr;
                    res[rt][ct][e] += c;
                    local_rq += rr * rr;
                    if (t < 2)
                        s_A[(wrow + rt * 16 + qd * 4 + e) * SA + ct * 16 + nn] = f2bf(rr);
                }
    }

    // restored -> s_A bf16 (wave-private)
    #pragma unroll
    for (int rt = 0; rt < 2; ++rt)
        #pragma unroll
        for (int ct = 0; ct < 8; ++ct)
            #pragma unroll
            for (int e = 0; e < 4; ++e)
                s_A[(wrow + rt * 16 + qd * 4 + e) * SA + ct * 16 + nn] = f2bf(res[rt][ct][e]);

    // ---- Phase 3: recon = restored @ Wdec^T; rounds 20..27, diff vs fp32 emb ----
    float local_rec = 0.f;
    {
        bf16x8 af[2][4];
        #pragma unroll
        for (int rt = 0; rt < 2; ++rt)
            #pragma unroll
            for (int ks = 0; ks < 4; ++ks)
                af[rt][ks] = *(const bf16x8*)&s_A[(wrow + rt * 16 + nn) * SA + ks * 32 + qd * 8];
        #pragma unroll
        for (int rl = 0; rl < 8; ++rl) {
            const int r = 20 + rl;
            if (r + 1 < NROUND) STAGE(r + 1, cur ^ 1);
            __builtin_amdgcn_s_setprio(1);
            #pragma unroll
            for (int ctc = 0; ctc < 4; ++ctc) {
                f32x4 r0 = {0.f,0.f,0.f,0.f}, r1 = {0.f,0.f,0.f,0.f};
                #pragma unroll
                for (int ks = 0; ks < 4; ++ks) {
                    bf16x8 bf = *(const bf16x8*)&s_B[cur][(ctc * 4 + ks) * 512 + lane * 8];
                    r0 = __builtin_amdgcn_mfma_f32_16x16x32_bf16(af[0][ks], bf, r0, 0, 0, 0);
                    r1 = __builtin_amdgcn_mfma_f32_16x16x32_bf16(af[1][ks], bf, r1, 0, 0, 0);
                }
                __builtin_amdgcn_s_setprio(0);
                const int col = rl * 64 + ctc * 16 + nn;
                #pragma unroll
                for (int e = 0; e < 4; ++e) {
                    const float e0 = emb[(blkRow + wrow +      qd * 4 + e) * D_IN + col];
                    const float e1 = emb[(blkRow + wrow + 16 + qd * 4 + e) * D_IN + col];
                    const float d0 = r0[e] - e0;
                    const float d1 = r1[e] - e1;
                    local_rec += d0 * d0 + d1 * d1;
                }
                __builtin_amdgcn_s_setprio(1);
            }
            __builtin_amdgcn_s_setprio(0);
            if (rl < 7) __syncthreads();
            cur ^= 1;
        }
    }
#undef STAGE

    // ---- wave shuffle reduce, one atomic pair per wave ----
    float r1 = local_rq, r2 = local_rec;
    #pragma unroll
    for (int m = 32; m >= 1; m >>= 1) { r1 += __shfl_xor(r1, m); r2 += __shfl_xor(r2, m); }
    if (lane == 0) { atomicAdd(acc_rq, r1); atomicAdd(acc_recon, r2); }
}

__global__ void rqvae_finalize(const float* __restrict__ acc,
                               const int* __restrict__ used,
                               float* __restrict__ out)
{
    __shared__ int s_sum[4];
    const int tid = threadIdx.x;
    for (int t = 0; t < 3; ++t) {
        int v = (used[t * K_CODES + tid] != 0) ? 1 : 0;
        #pragma unroll
        for (int off = 32; off >= 1; off >>= 1) v += __shfl_down(v, off);
        if ((tid & 63) == 0) s_sum[tid >> 6] = v;
        __syncthreads();
        if (tid == 0) out[3 + t] = (float)(s_sum[0] + s_sum[1] + s_sum[2] + s_sum[3]);
        __syncthreads();
    }
    if (tid == 0) {
        const float rq    = 1.25f * acc[0] / ((float)N_ROWS * 128.0f);
        const float recon =         acc[1] / ((float)N_ROWS * 512.0f);
        out[0] = recon + rq;
        out[1] = recon;
        out[2] = rq;
    }
}

extern "C" void kernel_launch(void* const* d_in, const int* in_sizes, int n_in,
                              void* d_out, int out_size, void* d_ws, size_t ws_size,
                              hipStream_t stream) {
    const float* emb  = (const float*)d_in[0];
    const float* Wenc = (const float*)d_in[1];
    const float* Wdec = (const float*)d_in[2];
    const float* cb0  = (const float*)d_in[3];
    const float* cb1  = (const float*)d_in[4];
    const float* cb2  = (const float*)d_in[5];

    // workspace layout (bytes): [0] 2 f32 acc | [64] 768 int used | [3200] 768 f32 norms | [8192] 448KB bf16 frags
    float* ws_f  = (float*)d_ws;
    int*   used  = (int*)((char*)d_ws + 64);
    float* norms = (float*)((char*)d_ws + 3200);
    unsigned short* wsb = (unsigned short*)((char*)d_ws + 8192);

    hipMemsetAsync(d_ws, 0, 3200, stream);
    rqvae_prep<<<115, NT, 0, stream>>>(Wenc, Wdec, cb0, cb1, cb2, wsb, norms);
    rqvae_main<<<NBLK, NT, 0, stream>>>(emb, cb0, cb1, cb2, wsb, norms,
                                        ws_f + 0, ws_f + 1, used);
    rqvae_finalize<<<1, K_CODES, 0, stream>>>(ws_f, used, (float*)d_out);
}

// Round 4
// 578.283 us; speedup vs baseline: 1.1619x; 1.0404x over previous
//
#include <hip/hip_runtime.h>

#define N_ROWS   131072
#define D_IN     512
#define D_H      128
#define K_CODES  256
#define NT       256          // 4 waves
#define RPB      128          // rows per block: 32 per wave (2 x 16-row MFMA tiles)
#define NBLK     (N_ROWS / RPB)
#define SA       136          // s_A row stride in bf16 elems (272 B, breaks power-of-2)
#define NROUND   28           // 28 x 16KB B rounds = whole wsb, consumed linearly

typedef __attribute__((ext_vector_type(8))) short bf16x8;
typedef __attribute__((ext_vector_type(4))) float f32x4;

__device__ inline unsigned short f2bf(float f) {
    unsigned u = __float_as_uint(f);
    return (unsigned short)((u + 0x7FFFu + ((u >> 16) & 1u)) >> 16);
}
__device__ inline ushort4 f2bf4(float4 v) {
    return make_ushort4(f2bf(v.x), f2bf(v.y), f2bf(v.z), f2bf(v.w));
}
__device__ inline bf16x8 f2bf8(float4 a, float4 b) {
    bf16x8 r;
    r[0] = (short)f2bf(a.x); r[1] = (short)f2bf(a.y); r[2] = (short)f2bf(a.z); r[3] = (short)f2bf(a.w);
    r[4] = (short)f2bf(b.x); r[5] = (short)f2bf(b.y); r[6] = (short)f2bf(b.z); r[7] = (short)f2bf(b.w);
    return r;
}

// async global->LDS DMA, 16B per lane; LDS dest is wave-uniform base + lane*16
typedef const __attribute__((address_space(1))) void* gv_t;
typedef __attribute__((address_space(3))) void* lv_t;
__device__ __forceinline__ void gll16(const unsigned short* g, unsigned short* l) {
    __builtin_amdgcn_global_load_lds((gv_t)g, (lv_t)l, 16, 0, 0);
}

// ---------------- prep: reorder weights/codebooks into MFMA B-fragment order ----------------
// B-fragment order: frag(ct,ks) is 64 lanes x 8 bf16, lane = qd*16+nn holds
// B[n = ct*16+nn][k = ks*32 + qd*8 + j], j=0..7.  One 32KB "round" = 8 ct x 4 ks.
// wsb layout (ushorts): [0..65535] Wenc rounds kc=0..3 | [65536..163839] cb (t,half) rounds | [163840..229375] Wdec rounds c=0..3
__global__ void rqvae_prep(const float* __restrict__ Wenc,
                           const float* __restrict__ Wdec,
                           const float* __restrict__ cb0,
                           const float* __restrict__ cb1,
                           const float* __restrict__ cb2,
                           unsigned short* __restrict__ wsb,
                           float* __restrict__ norms)
{
    const int tid = threadIdx.x;
    const int b = blockIdx.x;
    const float* cbs[3] = {cb0, cb1, cb2};
    if (b < 112) {
        const int g = b * 256 + tid;            // ushort8 group id, 0..28671
        const int lane = g & 63, ks = (g >> 6) & 3, ct = (g >> 8) & 7;
        const int nn = lane & 15, qd = lane >> 4;
        const float* src;
        if (g < 8192) {                         // Wenc: kc = g>>11
            const int kc = g >> 11;
            src = Wenc + (ct * 16 + nn) * D_IN + kc * 128 + ks * 32 + qd * 8;
        } else if (g < 20480) {                 // cb: t = (g-8192)>>12, half = bit 11
            const int r = g - 8192;
            const int t = r >> 12, half = (r >> 11) & 1;
            src = cbs[t] + (long)(half * 128 + ct * 16 + nn) * D_H + ks * 32 + qd * 8;
        } else {                                // Wdec: c = (g-20480)>>11
            const int r = g - 20480;
            const int c = r >> 11;
            src = Wdec + (long)(c * 128 + ct * 16 + nn) * D_H + ks * 32 + qd * 8;
        }
        float4 v0 = *(const float4*)(src);
        float4 v1 = *(const float4*)(src + 4);
        *(ushort4*)(wsb + (long)g * 8)     = f2bf4(v0);
        *(ushort4*)(wsb + (long)g * 8 + 4) = f2bf4(v1);
    } else {
        const int t = b - 112;                  // norm blocks: one code per thread
        const float4* r = (const float4*)(cbs[t] + (long)tid * D_H);
        float s = 0.f;
        #pragma unroll
        for (int d = 0; d < 32; ++d) { float4 v = r[d]; s += v.x*v.x + v.y*v.y + v.z*v.z + v.w*v.w; }
        norms[t * K_CODES + tid] = -0.5f * s;
    }
}

// ---------------- main ----------------
// Round-0 geometry (RPB=128, 4 waves, 2 blocks/CU) + double-buffered 28-round
// global_load_lds pipeline: STAGE(r+1 -> buf^1) ; MFMA(buf) ; __syncthreads.
// The syncthreads' vmcnt(0) drain lands AFTER a full compute phase, so the
// L2 stage latency is hidden. ALL round loops are unroll(1) and res[] is
// initialized after phase 1: at launch_bounds(256,2) the unified reg budget
// is 256/wave and rem+res already take 128 AGPRs -- round 3's unrolled bodies
// spilled 223KB/block to scratch (WRITE_SIZE 228MB). Keep pressure minimal.
__global__ __launch_bounds__(NT, 2) void rqvae_main(
    const float* __restrict__ emb,
    const float* __restrict__ cb0,
    const float* __restrict__ cb1,
    const float* __restrict__ cb2,
    const unsigned short* __restrict__ wsb,
    const float* __restrict__ norms,
    float* __restrict__ acc_rq,
    float* __restrict__ acc_recon,
    int* __restrict__ used)
{
    __shared__ unsigned short s_A[RPB * SA];   // 34816 B: latent/rem/restored, wave-private rows
    __shared__ unsigned short s_B[2][8192];    // 32768 B: double-buffered 16KB B rounds
    __shared__ float s_cn[3 * K_CODES];        // 3072 B  -> total 70656 B, 2 blocks/CU

    const int tid  = threadIdx.x;
    const int wv   = tid >> 6;
    const int lane = tid & 63;
    const int nn   = lane & 15;
    const int qd   = lane >> 4;
    const int wrow = wv * 32;                  // this wave's 32 rows in the block
    const long blkRow = (long)blockIdx.x * RPB;
    const float* cbs[3] = {cb0, cb1, cb2};

    for (int i = tid; i < 3 * K_CODES; i += NT) s_cn[i] = norms[i];

#define STAGE(r, buf) do {                                                      \
        const unsigned short* _s = wsb + (r) * 8192;                            \
        _Pragma("unroll")                                                       \
        for (int _i = 0; _i < 4; ++_i)                                          \
            gll16(_s + _i * 2048 + wv * 512 + lane * 8,                         \
                  &s_B[buf][_i * 2048 + wv * 512]);                             \
    } while (0)

    STAGE(0, 0);
    __syncthreads();                           // round-0 data + s_cn visible
    int cur = 0;

    f32x4 rem[2][8];
    #pragma unroll
    for (int rt = 0; rt < 2; ++rt)
        #pragma unroll
        for (int ct = 0; ct < 8; ++ct) rem[rt][ct] = {0.f,0.f,0.f,0.f};

    // ---- Phase 1: latent = emb @ Wenc^T; rounds 0..7, A direct global->reg ----
    #pragma unroll 1
    for (int kc = 0; kc < 4; ++kc) {
        STAGE(kc * 2 + 1, cur ^ 1);            // prefetch next round before the A-load stall
        bf16x8 af[2][4];
        #pragma unroll
        for (int rt = 0; rt < 2; ++rt) {
            const float* arow = emb + (blkRow + wrow + rt * 16 + nn) * D_IN + kc * 128 + qd * 8;
            #pragma unroll
            for (int ks = 0; ks < 4; ++ks)
                af[rt][ks] = f2bf8(*(const float4*)(arow + ks * 32), *(const float4*)(arow + ks * 32 + 4));
        }
        // round kc*2: ct = 0..3
        __builtin_amdgcn_s_setprio(1);
        #pragma unroll
        for (int ctc = 0; ctc < 4; ++ctc)
            #pragma unroll
            for (int ks = 0; ks < 4; ++ks) {
                bf16x8 bf = *(const bf16x8*)&s_B[cur][(ctc * 4 + ks) * 512 + lane * 8];
                rem[0][ctc] = __builtin_amdgcn_mfma_f32_16x16x32_bf16(af[0][ks], bf, rem[0][ctc], 0, 0, 0);
                rem[1][ctc] = __builtin_amdgcn_mfma_f32_16x16x32_bf16(af[1][ks], bf, rem[1][ctc], 0, 0, 0);
            }
        __builtin_amdgcn_s_setprio(0);
        __syncthreads(); cur ^= 1;
        STAGE(kc * 2 + 2, cur ^ 1);            // kc=3 stages round 8 = first phase-2 round
        // round kc*2+1: ct = 4..7
        __builtin_amdgcn_s_setprio(1);
        #pragma unroll
        for (int ctc = 0; ctc < 4; ++ctc)
            #pragma unroll
            for (int ks = 0; ks < 4; ++ks) {
                bf16x8 bf = *(const bf16x8*)&s_B[cur][(ctc * 4 + ks) * 512 + lane * 8];
                rem[0][4 + ctc] = __builtin_amdgcn_mfma_f32_16x16x32_bf16(af[0][ks], bf, rem[0][4 + ctc], 0, 0, 0);
                rem[1][4 + ctc] = __builtin_amdgcn_mfma_f32_16x16x32_bf16(af[1][ks], bf, rem[1][4 + ctc], 0, 0, 0);
            }
        __builtin_amdgcn_s_setprio(0);
        __syncthreads(); cur ^= 1;
    }

    // latent -> s_A bf16 (wave-private rows); res initialized HERE (shorter AGPR live range)
    f32x4 res[2][8];
    #pragma unroll
    for (int rt = 0; rt < 2; ++rt)
        #pragma unroll
        for (int ct = 0; ct < 8; ++ct) {
            res[rt][ct] = {0.f,0.f,0.f,0.f};
            #pragma unroll
            for (int e = 0; e < 4; ++e)
                s_A[(wrow + rt * 16 + qd * 4 + e) * SA + ct * 16 + nn] = f2bf(rem[rt][ct][e]);
        }

    // ---- Phase 2: three RQ stages; rounds 8..19 (4 x 16KB per stage) ----
    float local_rq = 0.f;
    #pragma unroll 1
    for (int t = 0; t < 3; ++t) {
        const float* __restrict__ cb = cbs[t];
        float bv[2][4]; int bi[2][4];
        #pragma unroll
        for (int rt = 0; rt < 2; ++rt)
            #pragma unroll
            for (int e = 0; e < 4; ++e) { bv[rt][e] = -3.402823466e38f; bi[rt][e] = 0; }

        bf16x8 af[2][4];
        #pragma unroll
        for (int rt = 0; rt < 2; ++rt)
            #pragma unroll
            for (int ks = 0; ks < 4; ++ks)
                af[rt][ks] = *(const bf16x8*)&s_A[(wrow + rt * 16 + nn) * SA + ks * 32 + qd * 8];

        #pragma unroll 1
        for (int rl = 0; rl < 4; ++rl) {
            STAGE(8 + t * 4 + rl + 1, cur ^ 1);            // <= round 20, always valid
            __builtin_amdgcn_s_setprio(1);
            #pragma unroll
            for (int ctc = 0; ctc < 4; ++ctc) {
                f32x4 s0 = {0.f,0.f,0.f,0.f}, s1 = {0.f,0.f,0.f,0.f};
                #pragma unroll
                for (int ks = 0; ks < 4; ++ks) {
                    bf16x8 bf = *(const bf16x8*)&s_B[cur][(ctc * 4 + ks) * 512 + lane * 8];
                    s0 = __builtin_amdgcn_mfma_f32_16x16x32_bf16(af[0][ks], bf, s0, 0, 0, 0);
                    s1 = __builtin_amdgcn_mfma_f32_16x16x32_bf16(af[1][ks], bf, s1, 0, 0, 0);
                }
                const int code = rl * 64 + ctc * 16 + nn;
                const float cn = s_cn[t * K_CODES + code];
                #pragma unroll
                for (int e = 0; e < 4; ++e) {
                    const float v0 = s0[e] + cn;
                    if (v0 > bv[0][e] || (v0 == bv[0][e] && code < bi[0][e])) { bv[0][e] = v0; bi[0][e] = code; }
                    const float v1 = s1[e] + cn;
                    if (v1 > bv[1][e] || (v1 == bv[1][e] && code < bi[1][e])) { bv[1][e] = v1; bi[1][e] = code; }
                }
            }
            __builtin_amdgcn_s_setprio(0);
            __syncthreads(); cur ^= 1;
        }
        // argmax over the 16 nn-lanes of each quad (tie -> lowest index)
        #pragma unroll
        for (int rt = 0; rt < 2; ++rt)
            #pragma unroll
            for (int e = 0; e < 4; ++e) {
                float v = bv[rt][e]; int i0 = bi[rt][e];
                #pragma unroll
                for (int m = 8; m >= 1; m >>= 1) {
                    const float ov = __shfl_xor(v, m);
                    const int   oi = __shfl_xor(i0, m);
                    if (ov > v || (ov == v && oi < i0)) { v = ov; i0 = oi; }
                }
                bi[rt][e] = i0;
                if (nn == 0) used[t * K_CODES + i0] = 1;
            }
        // update rem/res with fp32 codebook rows
        #pragma unroll
        for (int rt = 0; rt < 2; ++rt)
            #pragma unroll
            for (int ct = 0; ct < 8; ++ct)
                #pragma unroll
                for (int e = 0; e < 4; ++e) {
                    const float c = cb[(long)bi[rt][e] * D_H + ct * 16 + nn];
                    const float rr = rem[rt][ct][e] - c;
                    rem[rt][ct][e] = rr;
                    res[rt][ct][e] += c;
                    local_rq += rr * rr;
                    if (t < 2)
                        s_A[(wrow + rt * 16 + qd * 4 + e) * SA + ct * 16 + nn] = f2bf(rr);
                }
    }

    // restored -> s_A bf16 (wave-private)
    #pragma unroll
    for (int rt = 0; rt < 2; ++rt)
        #pragma unroll
        for (int ct = 0; ct < 8; ++ct)
            #pragma unroll
            for (int e = 0; e < 4; ++e)
                s_A[(wrow + rt * 16 + qd * 4 + e) * SA + ct * 16 + nn] = f2bf(res[rt][ct][e]);

    // ---- Phase 3: recon = restored @ Wdec^T; rounds 20..27, diff vs fp32 emb ----
    float local_rec = 0.f;
    {
        bf16x8 af[2][4];
        #pragma unroll
        for (int rt = 0; rt < 2; ++rt)
            #pragma unroll
            for (int ks = 0; ks < 4; ++ks)
                af[rt][ks] = *(const bf16x8*)&s_A[(wrow + rt * 16 + nn) * SA + ks * 32 + qd * 8];
        #pragma unroll 1
        for (int rl = 0; rl < 8; ++rl) {
            if (rl < 7) STAGE(21 + rl, cur ^ 1);
            __builtin_amdgcn_s_setprio(1);
            #pragma unroll
            for (int ctc = 0; ctc < 4; ++ctc) {
                f32x4 r0 = {0.f,0.f,0.f,0.f}, r1 = {0.f,0.f,0.f,0.f};
                #pragma unroll
                for (int ks = 0; ks < 4; ++ks) {
                    bf16x8 bf = *(const bf16x8*)&s_B[cur][(ctc * 4 + ks) * 512 + lane * 8];
                    r0 = __builtin_amdgcn_mfma_f32_16x16x32_bf16(af[0][ks], bf, r0, 0, 0, 0);
                    r1 = __builtin_amdgcn_mfma_f32_16x16x32_bf16(af[1][ks], bf, r1, 0, 0, 0);
                }
                const int col = rl * 64 + ctc * 16 + nn;
                #pragma unroll
                for (int e = 0; e < 4; ++e) {
                    const float e0 = emb[(blkRow + wrow +      qd * 4 + e) * D_IN + col];
                    const float e1 = emb[(blkRow + wrow + 16 + qd * 4 + e) * D_IN + col];
                    const float d0 = r0[e] - e0;
                    const float d1 = r1[e] - e1;
                    local_rec += d0 * d0 + d1 * d1;
                }
            }
            __builtin_amdgcn_s_setprio(0);
            if (rl < 7) __syncthreads();
            cur ^= 1;
        }
    }
#undef STAGE

    // ---- wave shuffle reduce, one atomic pair per wave ----
    float r1 = local_rq, r2 = local_rec;
    #pragma unroll
    for (int m = 32; m >= 1; m >>= 1) { r1 += __shfl_xor(r1, m); r2 += __shfl_xor(r2, m); }
    if (lane == 0) { atomicAdd(acc_rq, r1); atomicAdd(acc_recon, r2); }
}

__global__ void rqvae_finalize(const float* __restrict__ acc,
                               const int* __restrict__ used,
                               float* __restrict__ out)
{
    __shared__ int s_sum[4];
    const int tid = threadIdx.x;
    for (int t = 0; t < 3; ++t) {
        int v = (used[t * K_CODES + tid] != 0) ? 1 : 0;
        #pragma unroll
        for (int off = 32; off >= 1; off >>= 1) v += __shfl_down(v, off);
        if ((tid & 63) == 0) s_sum[tid >> 6] = v;
        __syncthreads();
        if (tid == 0) out[3 + t] = (float)(s_sum[0] + s_sum[1] + s_sum[2] + s_sum[3]);
        __syncthreads();
    }
    if (tid == 0) {
        const float rq    = 1.25f * acc[0] / ((float)N_ROWS * 128.0f);
        const float recon =         acc[1] / ((float)N_ROWS * 512.0f);
        out[0] = recon + rq;
        out[1] = recon;
        out[2] = rq;
    }
}

extern "C" void kernel_launch(void* const* d_in, const int* in_sizes, int n_in,
                              void* d_out, int out_size, void* d_ws, size_t ws_size,
                              hipStream_t stream) {
    const float* emb  = (const float*)d_in[0];
    const float* Wenc = (const float*)d_in[1];
    const float* Wdec = (const float*)d_in[2];
    const float* cb0  = (const float*)d_in[3];
    const float* cb1  = (const float*)d_in[4];
    const float* cb2  = (const float*)d_in[5];

    // workspace layout (bytes): [0] 2 f32 acc | [64] 768 int used | [3200] 768 f32 norms | [8192] 448KB bf16 frags
    float* ws_f  = (float*)d_ws;
    int*   used  = (int*)((char*)d_ws + 64);
    float* norms = (float*)((char*)d_ws + 3200);
    unsigned short* wsb = (unsigned short*)((char*)d_ws + 8192);

    hipMemsetAsync(d_ws, 0, 3200, stream);
    rqvae_prep<<<115, NT, 0, stream>>>(Wenc, Wdec, cb0, cb1, cb2, wsb, norms);
    rqvae_main<<<NBLK, NT, 0, stream>>>(emb, cb0, cb1, cb2, wsb, norms,
                                        ws_f + 0, ws_f + 1, used);
    rqvae_finalize<<<1, K_CODES, 0, stream>>>(ws_f, used, (float*)d_out);
}